// Round 3
// baseline (324.708 us; speedup 1.0000x reference)
//
#include <hip/hip_runtime.h>

#define DD 128
#define NC 10
#define NT 15
#define NCT 150
#define NCOLS 450
#define NCOLP 464
#define BTRAIN 100000
#define BTEST 100000
#define NB 100032
#define GROWS 70050   // 150 * 467 needed param rows

typedef __attribute__((ext_vector_type(8))) __bf16 bf16x8;
typedef __attribute__((ext_vector_type(4))) float f32x4;
typedef __attribute__((ext_vector_type(8))) unsigned short u16x8;

static __device__ __forceinline__ unsigned short f2bf(float f) {
  unsigned int u = __builtin_bit_cast(unsigned int, f);
  u = (u + 0x7FFFu + ((u >> 16) & 1u)) >> 16;
  return (unsigned short)u;
}

// ---------- K1: column sums of X_train ----------
__global__ void __launch_bounds__(256) k_colsum(const float* __restrict__ X, float* __restrict__ acc) {
  int tid = threadIdx.x;
  int gid = blockIdx.x * 256 + tid;
  int stride = gridDim.x * 256;
  float sx = 0.f, sy = 0.f, sz = 0.f, sw = 0.f;
  const float4* Xv = (const float4*)X;
  for (int i = gid; i < BTRAIN * 32; i += stride) {
    float4 v = Xv[i];
    sx += v.x; sy += v.y; sz += v.z; sw += v.w;
  }
  __shared__ float red[256][4];
  red[tid][0] = sx; red[tid][1] = sy; red[tid][2] = sz; red[tid][3] = sw;
  __syncthreads();
  for (int off = 128; off >= 32; off >>= 1) {
    if (tid < off) {
      red[tid][0] += red[tid + off][0];
      red[tid][1] += red[tid + off][1];
      red[tid][2] += red[tid + off][2];
      red[tid][3] += red[tid + off][3];
    }
    __syncthreads();
  }
  if (tid < 32) {
    atomicAdd(&acc[tid * 4 + 0], red[tid][0]);
    atomicAdd(&acc[tid * 4 + 1], red[tid][1]);
    atomicAdd(&acc[tid * 4 + 2], red[tid][2]);
    atomicAdd(&acc[tid * 4 + 3], red[tid][3]);
  }
}

// ---------- K2a: mean finalize + encoder layer1 + LN + relu ----------
__global__ void __launch_bounds__(512) k_enc1(const float* __restrict__ acc, const float* __restrict__ W1,
                                              const float* __restrict__ b1, const float* __restrict__ g,
                                              const float* __restrict__ bb, float* __restrict__ out) {
  __shared__ float mS[DD];
  __shared__ float red[512];
  int t = threadIdx.x;
  if (t < DD) mS[t] = acc[t] * (1.0f / BTRAIN);
  __syncthreads();
  float z = b1[t];
  const float4* w = (const float4*)(W1 + t * DD);
#pragma unroll
  for (int j = 0; j < DD / 4; ++j) {
    float4 wv = w[j];
    z += wv.x * mS[4 * j] + wv.y * mS[4 * j + 1] + wv.z * mS[4 * j + 2] + wv.w * mS[4 * j + 3];
  }
  red[t] = z; __syncthreads();
  for (int off = 256; off > 0; off >>= 1) { if (t < off) red[t] += red[t + off]; __syncthreads(); }
  float m = red[0] * (1.0f / 512.0f); __syncthreads();
  float d = z - m;
  red[t] = d * d; __syncthreads();
  for (int off = 256; off > 0; off >>= 1) { if (t < off) red[t] += red[t + off]; __syncthreads(); }
  float v = red[0] * (1.0f / 512.0f);
  out[t] = fmaxf(d * rsqrtf(v + 1e-5f) * g[t] + bb[t], 0.0f);
}

// ---------- generic wave-per-row matvec, K=512 ----------
template <int RELU>
__global__ void __launch_bounds__(256) k_matvec512(const float* __restrict__ W, const float* __restrict__ x,
                                                   const float* __restrict__ bias, float* __restrict__ out, int rows) {
  int wv = threadIdx.x >> 6, lane = threadIdx.x & 63;
  int row = blockIdx.x * 4 + wv;
  if (row >= rows) return;
  const float4* wr = (const float4*)(W + (size_t)row * 512) + lane * 2;
  const float4* xv = (const float4*)x + lane * 2;
  float4 a0 = wr[0], a1 = wr[1], x0 = xv[0], x1 = xv[1];
  float s = a0.x * x0.x + a0.y * x0.y + a0.z * x0.z + a0.w * x0.w
          + a1.x * x1.x + a1.y * x1.y + a1.z * x1.z + a1.w * x1.w;
#pragma unroll
  for (int off = 32; off > 0; off >>= 1) s += __shfl_down(s, off);
  if (lane == 0) {
    s += bias[row];
    if (RELU) s = fmaxf(s, 0.0f);
    out[row] = s;
  }
}

// ---------- K2c: LN + relu on a 512-vector ----------
__global__ void __launch_bounds__(512) k_ln(const float* __restrict__ z, const float* __restrict__ g,
                                            const float* __restrict__ bb, float* __restrict__ out) {
  __shared__ float red[512];
  int t = threadIdx.x;
  float zv = z[t];
  red[t] = zv; __syncthreads();
  for (int off = 256; off > 0; off >>= 1) { if (t < off) red[t] += red[t + off]; __syncthreads(); }
  float m = red[0] * (1.0f / 512.0f); __syncthreads();
  float d = zv - m;
  red[t] = d * d; __syncthreads();
  for (int off = 256; off > 0; off >>= 1) { if (t < off) red[t] += red[t + off]; __syncthreads(); }
  float v = red[0] * (1.0f / 512.0f);
  out[t] = fmaxf(d * rsqrtf(v + 1e-5f) * g[t] + bb[t], 0.0f);
}

// ---------- K4: gather-matvec of needed head_W2 rows ----------
__global__ void __launch_bounds__(256) k_params(const float* __restrict__ W2, const float* __restrict__ hh,
                                                const float* __restrict__ b2, unsigned short* __restrict__ Wb,
                                                float* __restrict__ sb, float* __restrict__ leaf) {
  int wv = threadIdx.x >> 6, lane = threadIdx.x & 63;
  int R = blockIdx.x * 4 + wv;
  if (R >= GROWS) return;
  int ctIdx = R / 467;
  int w = R - ctIdx * 467;
  int c = ctIdx / 15;
  int t = ctIdx - c * 15;
  int p;
  if (w < 384) p = t * 983 + w;
  else if (w < 387) p = t * 983 + 896 + (w - 384);
  else p = t * 983 + 903 + (w - 387);
  size_t rowoff = (size_t)c * 14745 + p;
  const float4* wr = (const float4*)(W2 + rowoff * 512) + lane * 2;
  const float4* xv = (const float4*)(hh + c * 512) + lane * 2;
  float4 a0 = wr[0], a1 = wr[1], x0 = xv[0], x1 = xv[1];
  float s = a0.x * x0.x + a0.y * x0.y + a0.z * x0.z + a0.w * x0.w
          + a1.x * x1.x + a1.y * x1.y + a1.z * x1.z + a1.w * x1.w;
#pragma unroll
  for (int off = 32; off > 0; off >>= 1) s += __shfl_down(s, off);
  if (lane == 0) {
    s += b2[rowoff];
    if (w < 384) {
      int i = w >> 7, d = w & 127;
      Wb[(size_t)(ctIdx * 3 + i) * DD + d] = f2bf(s);
    } else if (w < 387) {
      sb[ctIdx * 3 + (w - 384)] = s;
    } else {
      leaf[ctIdx * 80 + (w - 387)] = s;
    }
  }
}

// ---------- K5: tree_out softmax * w_t / C table ----------
__global__ void k_to(const float* __restrict__ leaf, const float* __restrict__ tw, float* __restrict__ TO) {
  int q = blockIdx.x * 256 + threadIdx.x;
  if (q >= NCT * 8) return;
  int ct = q >> 3, l = q & 7;
  int t = ct % 15;
  float mx = tw[0];
  for (int i = 1; i < 15; ++i) mx = fmaxf(mx, tw[i]);
  float wsum = 0.0f;
  for (int i = 0; i < 15; ++i) wsum += __expf(tw[i] - mx);
  float wt = __expf(tw[t] - mx) / wsum;
  const float* lr = leaf + ct * 80 + l * 10;
  float m2 = lr[0];
#pragma unroll
  for (int k = 1; k < 10; ++k) m2 = fmaxf(m2, lr[k]);
  float ex[10]; float es = 0.0f;
#pragma unroll
  for (int k = 0; k < 10; ++k) { ex[k] = __expf(lr[k] - m2); es += ex[k]; }
  float sc = wt / (es * (float)NC);
#pragma unroll
  for (int k = 0; k < 10; ++k) TO[ct * 80 + l * 10 + k] = ex[k] * sc;
}

// ---------- K6: routes GEMM (bf16 MFMA) + sigmoid, col-major f16 out ----------
__global__ void __launch_bounds__(256) k_routes(const float* __restrict__ X, const unsigned short* __restrict__ Wb,
                                                const float* __restrict__ sb, unsigned short* __restrict__ routes) {
  __shared__ unsigned short Xs[64][144];   // bf16 bits, 288B rows (16B aligned)
  __shared__ _Float16 Rs[64][466];         // 932B rows -> 2-way-free transpose reads
  int tid = threadIdx.x;
  int b0 = blockIdx.x * 64;
  {
    int row = tid >> 2, seg = tid & 3;
    int gb = b0 + row;
    const float4* xr = (const float4*)(X + (size_t)gb * DD) + seg * 8;
#pragma unroll
    for (int j2 = 0; j2 < 4; ++j2) {
      u16x8 u;
      if (gb < BTEST) {
        float4 va = xr[2 * j2], vb = xr[2 * j2 + 1];
        u[0] = f2bf(va.x); u[1] = f2bf(va.y); u[2] = f2bf(va.z); u[3] = f2bf(va.w);
        u[4] = f2bf(vb.x); u[5] = f2bf(vb.y); u[6] = f2bf(vb.z); u[7] = f2bf(vb.w);
      } else {
#pragma unroll
        for (int j = 0; j < 8; ++j) u[j] = 0;
      }
      *(u16x8*)&Xs[row][seg * 32 + j2 * 8] = u;
    }
  }
  __syncthreads();
  int wv = tid >> 6, lane = tid & 63;
  int m = lane & 15, g = lane >> 4;
  // A fragments: lane holds A[row=m][k = g*8 + j] per 16x16x32 step
  bf16x8 A[4][4];
#pragma unroll
  for (int rt = 0; rt < 4; ++rt)
#pragma unroll
    for (int ks = 0; ks < 4; ++ks)
      A[rt][ks] = __builtin_bit_cast(bf16x8, *(const u16x8*)&Xs[rt * 16 + m][ks * 32 + g * 8]);
  int start = (wv == 0) ? 0 : (1 + 7 * wv);  // tiles: 0-7, 8-14, 15-21, 22-28
  int cnt = (wv == 0) ? 8 : 7;
  for (int it = 0; it < cnt; ++it) {
    int col = (start + it) * 16 + m;
    f32x4 acc[4];
#pragma unroll
    for (int rt = 0; rt < 4; ++rt) acc[rt] = 0.0f;
#pragma unroll
    for (int ks = 0; ks < 4; ++ks) {
      bf16x8 Bf = __builtin_bit_cast(bf16x8, *(const u16x8*)&Wb[(size_t)col * DD + ks * 32 + g * 8]);
#pragma unroll
      for (int rt = 0; rt < 4; ++rt)
        acc[rt] = __builtin_amdgcn_mfma_f32_16x16x32_bf16(A[rt][ks], Bf, acc[rt], 0, 0, 0);
    }
    float sbv = sb[col];
#pragma unroll
    for (int rt = 0; rt < 4; ++rt)
#pragma unroll
      for (int r = 0; r < 4; ++r) {
        float pre = acc[rt][r] + sbv;
        float sg = 1.0f / (1.0f + __expf(-pre));
        Rs[rt * 16 + g * 4 + r][col] = (_Float16)sg;
      }
  }
  __syncthreads();
  int cidx = tid >> 6, ln = tid & 63;
  _Float16* rp = (_Float16*)routes;
  for (int c = cidx; c < NCOLS; c += 4)
    rp[(size_t)c * NB + b0 + ln] = Rs[ln][c];
}

// ---------- K7: tree combine (f32 output) ----------
__global__ void __launch_bounds__(256) k_combine(const unsigned short* __restrict__ routes_u,
                                                 const float* __restrict__ TO, float* __restrict__ out) {
  int b = blockIdx.x * 256 + threadIdx.x;
  if (b >= BTEST) return;
  const _Float16* routes = (const _Float16*)routes_u;
  float acc[10];
#pragma unroll
  for (int k = 0; k < 10; ++k) acc[k] = 0.0f;
  for (int ct = 0; ct < NCT; ++ct) {
    float l0 = (float)routes[(size_t)(3 * ct + 0) * NB + b];
    float l1 = (float)routes[(size_t)(3 * ct + 1) * NB + b];
    float l2 = (float)routes[(size_t)(3 * ct + 2) * NB + b];
    float n0 = 1.0f - l0, n1 = 1.0f - l1, n2 = 1.0f - l2;
    float p00 = l1 * l0, p01 = l1 * n0, p10 = n1 * l0, p11 = n1 * n0;
    float lp[8] = { l2 * p00, l2 * p01, l2 * p10, l2 * p11,
                    n2 * p00, n2 * p01, n2 * p10, n2 * p11 };
    const float* to = TO + ct * 80;  // uniform address -> scalar loads
#pragma unroll
    for (int l = 0; l < 8; ++l)
#pragma unroll
      for (int k = 0; k < 10; ++k)
        acc[k] = fmaf(lp[l], to[l * 10 + k], acc[k]);
  }
  float2* op = (float2*)(out + (size_t)b * 10);
#pragma unroll
  for (int j = 0; j < 5; ++j) {
    float2 v; v.x = acc[2 * j]; v.y = acc[2 * j + 1];
    op[j] = v;
  }
}

extern "C" void kernel_launch(void* const* d_in, const int* in_sizes, int n_in,
                              void* d_out, int out_size, void* d_ws, size_t ws_size,
                              hipStream_t stream) {
  const float* Xtr = (const float*)d_in[0];
  const float* Xte = (const float*)d_in[1];
  const float* eW1 = (const float*)d_in[2];
  const float* eb1 = (const float*)d_in[3];
  const float* g1  = (const float*)d_in[4];
  const float* bb1 = (const float*)d_in[5];
  const float* eW2 = (const float*)d_in[6];
  const float* eb2 = (const float*)d_in[7];
  const float* g2  = (const float*)d_in[8];
  const float* bb2 = (const float*)d_in[9];
  const float* hW1 = (const float*)d_in[10];
  const float* hb1 = (const float*)d_in[11];
  const float* hW2 = (const float*)d_in[12];
  const float* hb2 = (const float*)d_in[13];
  const float* tw  = (const float*)d_in[14];

  char* ws = (char*)d_ws;
  const size_t OFF_MEAN = 0;        // 512 B
  const size_t OFF_H1 = 4096;       // 2048 B
  const size_t OFF_Z2 = 8192;       // 2048 B
  const size_t OFF_H2 = 12288;      // 2048 B
  const size_t OFF_HH = 16384;      // 20480 B
  const size_t OFF_LEAF = 40960;    // 48000 B
  const size_t OFF_TO = 90112;      // 48000 B
  const size_t OFF_WB = 139264;     // 464*128*2 = 118784 B
  const size_t OFF_SB = 258048;     // 464*4 = 1856 B
  const size_t OFF_ROUTES = 262144; // 450*100032*2 = 90,028,800 B
  const size_t NEED = OFF_ROUTES + (size_t)NCOLS * NB * 2;
  if (ws_size < NEED) return;  // insufficient workspace -> fail loud (wrong output)

  float* mean_acc = (float*)(ws + OFF_MEAN);
  float* h1 = (float*)(ws + OFF_H1);
  float* z2 = (float*)(ws + OFF_Z2);
  float* h2 = (float*)(ws + OFF_H2);
  float* hhp = (float*)(ws + OFF_HH);
  float* leafp = (float*)(ws + OFF_LEAF);
  float* TOp = (float*)(ws + OFF_TO);
  unsigned short* Wb = (unsigned short*)(ws + OFF_WB);
  float* sbp = (float*)(ws + OFF_SB);
  unsigned short* routesp = (unsigned short*)(ws + OFF_ROUTES);

  (void)hipMemsetAsync(ws + OFF_MEAN, 0, 512, stream);
  (void)hipMemsetAsync(ws + OFF_WB, 0, 118784 + 1856, stream);  // Wb + sb (zero pads)

  k_colsum<<<1024, 256, 0, stream>>>(Xtr, mean_acc);
  k_enc1<<<1, 512, 0, stream>>>(mean_acc, eW1, eb1, g1, bb1, h1);
  k_matvec512<0><<<128, 256, 0, stream>>>(eW2, h1, eb2, z2, 512);
  k_ln<<<1, 512, 0, stream>>>(z2, g2, bb2, h2);
  k_matvec512<1><<<1280, 256, 0, stream>>>(hW1, h2, hb1, hhp, 5120);
  k_params<<<17513, 256, 0, stream>>>(hW2, hhp, hb2, Wb, sbp, leafp);
  k_to<<<5, 256, 0, stream>>>(leafp, tw, TOp);
  k_routes<<<1563, 256, 0, stream>>>(Xte, Wb, sbp, routesp);
  k_combine<<<391, 256, 0, stream>>>(routesp, TOp, (float*)d_out);
}